// Round 14
// baseline (95.472 us; speedup 1.0000x reference)
//
#include <hip/hip_runtime.h>
#include <hip/hip_bf16.h>
#include <math.h>

#define BB 256
#define FF 1024
#define GG 512
#define SS 512
#define EE 256
#define PP 8
#define TT 256

typedef __attribute__((ext_vector_type(8))) short bs8;     // 8 bf16
typedef __attribute__((ext_vector_type(4))) float f32x4;

__device__ __forceinline__ float sigmoidf_(float x) { return 1.0f / (1.0f + expf(-x)); }

__device__ __forceinline__ short f2bf(float f) {
    union { float f; unsigned u; } v; v.f = f;
    unsigned r = v.u + 0x7FFFu + ((v.u >> 16) & 1u);   // RNE
    return (short)(r >> 16);
}

union BPack { bs8 s; __hip_bfloat162 h[4]; };

__device__ __forceinline__ bs8 ld8cvt(const float* p) {
    float4 a = *(const float4*)p, b = *(const float4*)(p + 4);
    BPack u;
    u.h[0] = __float22bfloat162_rn({a.x, a.y});
    u.h[1] = __float22bfloat162_rn({a.z, a.w});
    u.h[2] = __float22bfloat162_rn({b.x, b.y});
    u.h[3] = __float22bfloat162_rn({b.z, b.w});
    return u.s;
}
__device__ __forceinline__ void ld8split(const float* p, bs8& ho, bs8& lo) {
    float4 a = *(const float4*)p, b = *(const float4*)(p + 4);
    float v[8] = {a.x, a.y, a.z, a.w, b.x, b.y, b.z, b.w};
    BPack uh, ul;
#pragma unroll
    for (int j = 0; j < 4; ++j) {
        __hip_bfloat162 h2 = __float22bfloat162_rn({v[2*j], v[2*j+1]});
        uh.h[j] = h2;
        float r0 = v[2*j]   - __low2float(h2);
        float r1 = v[2*j+1] - __high2float(h2);
        ul.h[j] = __float22bfloat162_rn({r0, r1});
    }
    ho = uh.s; lo = ul.s;
}

// async global->LDS, 16B per lane, linear LDS dest (wave-uniform base + lane*16)
__device__ __forceinline__ void gload16(const short* g, short* l) {
    __builtin_amdgcn_global_load_lds(
        (const __attribute__((address_space(1))) void*)g,
        (__attribute__((address_space(3))) void*)l,
        16, 0, 0);
}

// ---------------------------------------------------------------------------
// W slab layout (elements)
// ---------------------------------------------------------------------------
#define OWG_IH 0L
#define OWG_HH 2359296L
#define OWP_IH 3145728L
#define OWP_HH 5505024L
#define OWE_IH 6291456L
#define OWE_HH 6684672L
#define WTOT   6881280L

// block-range boundaries for k_mega
#define MB1 3360     // W slab conv          (3360 blocks)
#define MB2 3616     // attn_W hi/lo split   (256)
#define MB3 3744     // feature -> xg/fhi/flo(128)
#define MB4 3808     // h_g -> hg_bf         (64)
#define MB5 3840     // emotion0 -> emo_bf   (32)
#define MB6 4096     // gather               (256)
#define MBE 5120     // speaker copy         (1024)

__global__ __launch_bounds__(256) void k_mega(
        const float* __restrict__ Wg_ih, const float* __restrict__ Wg_hh,
        const float* __restrict__ Wp_ih, const float* __restrict__ Wp_hh,
        const float* __restrict__ We_ih, const float* __restrict__ We_hh,
        const float* __restrict__ attn_W, const float* __restrict__ feature_,
        const float* __restrict__ h_g, const float* __restrict__ emotion0,
        const float* __restrict__ mask, const float* __restrict__ sp0,
        short* __restrict__ Wbf, short* __restrict__ awhi, short* __restrict__ awlo,
        short* __restrict__ xg, short* __restrict__ fhi, short* __restrict__ flo,
        short* __restrict__ hg_bf, short* __restrict__ emo_bf, short* __restrict__ sel0_bf,
        float* __restrict__ sel0, int* __restrict__ spk, float* __restrict__ speaker_out) {
    int blk = blockIdx.x, tid = threadIdx.x;
    if (blk < MB1) {
        long i = (long)blk * 2048 + tid * 8;
        const float* src; long base;
        if      (i < OWG_HH) { src = Wg_ih; base = OWG_IH; }
        else if (i < OWP_IH) { src = Wg_hh; base = OWG_HH; }
        else if (i < OWP_HH) { src = Wp_ih; base = OWP_IH; }
        else if (i < OWE_IH) { src = Wp_hh; base = OWP_HH; }
        else if (i < OWE_HH) { src = We_ih; base = OWE_IH; }
        else                 { src = We_hh; base = OWE_HH; }
        *(bs8*)(Wbf + i) = ld8cvt(src + (i - base));
    } else if (blk < MB2) {
        long i = (long)(blk - MB1) * 2048 + tid * 8;
        bs8 h, l;
        ld8split(attn_W + i, h, l);
        *(bs8*)(awhi + i) = h;
        *(bs8*)(awlo + i) = l;
    } else if (blk < MB3) {
        long i = (long)(blk - MB2) * 2048 + tid * 8;
        bs8 h, l;
        ld8split(feature_ + i, h, l);
        *(bs8*)(fhi + i) = h;
        *(bs8*)(flo + i) = l;
        long b = i >> 10, c = i & 1023;
        *(bs8*)(xg + b * 1536 + c) = h;
    } else if (blk < MB4) {
        long i = (long)(blk - MB3) * 2048 + tid * 8;
        *(bs8*)(hg_bf + i) = ld8cvt(h_g + i);
    } else if (blk < MB5) {
        long i = (long)(blk - MB4) * 2048 + tid * 8;
        *(bs8*)(emo_bf + i) = ld8cvt(emotion0 + i);
    } else if (blk < MB6) {
        int b = blk - MB5;
        __shared__ int sid;
        if (tid == 0) {
            int best = 0; float bv = mask[b * PP];
            for (int p = 1; p < PP; ++p) { float v = mask[b * PP + p]; if (v > bv) { bv = v; best = p; } }
            sid = best; spk[b] = best;
        }
        __syncthreads();
        const float* src = sp0 + ((size_t)b * PP + sid) * SS;
        for (int j = tid; j < SS; j += 256) {
            float v = src[j];
            sel0[(size_t)b * SS + j] = v;
            short h = f2bf(v);
            sel0_bf[(size_t)b * SS + j] = h;
            xg[(size_t)b * 1536 + FF + j] = h;
        }
    } else {
        size_t i = ((size_t)(blk - MB6) * 256 + tid) * 4;
        *(float4*)(speaker_out + i) = *(const float4*)(sp0 + i);
    }
}

// ---------------------------------------------------------------------------
// Batched bf16 MFMA GEMM. BM=128 x BN=64 tiles, 8 waves (512 thr), BK=128.
// global_load_lds staging (width 16), pre-swizzled global source.
// Weight panels now re-read only 2x (vs 4x at BM=64). Bit-identical numerics.
// flags: 1 = split (A2=A_lo, Wl=W_lo; 3-MFMA compensated), 2 = accumulate.
// ---------------------------------------------------------------------------
struct GDesc {
    const short *A, *A2, *W, *Wl;
    float* C;
    int lda, lda2, kb, ldw, woff, ldc, K, nbn, flags;
};
struct GBatch {
    GDesc d[6];
    int start[7];
    int ng;
};

__global__ __launch_bounds__(512) void k_bgemm(GBatch gb) {
    __shared__ __align__(16) short Ash[16384], Asl[16384];   // 128 x 128
    __shared__ __align__(16) short Bsh[8192],  Bsl[8192];    // 64 x 128

    int bid = blockIdx.x;
    int g = 0;
    while (g + 1 < gb.ng && bid >= gb.start[g + 1]) ++g;
    GDesc d = gb.d[g];
    int local = bid - gb.start[g];
    int bn = local % d.nbn, bm = local / d.nbn;
    const bool split = (d.flags & 1) != 0;

    const int tid = threadIdx.x;
    const int lane = tid & 63, wid = tid >> 6;       // wid 0..7
    const int wr = wid >> 1, wc = wid & 1;           // wr 0..3, wc 0..1
    const int la = lane & 15, lk = lane >> 4;
    const int sw = la & 7;

    // staging map: wave wid covers A rows [wid*16, wid*16+16); instr c covers
    // rows wid*16 + c*4 + lane/16, granule lane&15 of the 128-col row.
    int srow[4], soff[4];
#pragma unroll
    for (int c = 0; c < 4; ++c) {
        srow[c] = wid * 16 + c * 4 + (lane >> 4);
        int gq = lane & 15;
        soff[c] = (gq >> 3) * 64 + (((gq & 7) ^ (srow[c] & 7)) * 8);  // pre-swizzled
    }
    short* Adst  = Ash + wid * 2048;
    short* Aldst = Asl + wid * 2048;
    // B staged by waves 0..3 only (64 rows)
    short* Bdst  = Bsh + wid * 2048;
    short* Bldst = Bsl + wid * 2048;

    f32x4 acc[2][2] = {};

    for (int k0 = 0; k0 < d.K; k0 += 128) {
        __syncthreads();   // previous iteration's LDS reads complete
        if (split) {
#pragma unroll
            for (int c = 0; c < 4; ++c) {
                size_t oa = (size_t)(bm * 128 + srow[c]) * d.lda + k0 + soff[c];
                gload16(d.A  + oa, Adst  + c * 512);
                gload16(d.A2 + oa, Aldst + c * 512);
            }
            if (wid < 4) {
#pragma unroll
                for (int c = 0; c < 4; ++c) {
                    size_t ow = (size_t)(bn * 64 + srow[c]) * d.ldw + d.woff + k0 + soff[c];
                    gload16(d.W  + ow, Bdst  + c * 512);
                    gload16(d.Wl + ow, Bldst + c * 512);
                }
            }
        } else {
            const short* Ab; int alda;
            if (k0 < d.kb) { Ab = d.A + k0; alda = d.lda; }
            else           { Ab = d.A2 + (k0 - d.kb); alda = d.lda2; }
#pragma unroll
            for (int c = 0; c < 4; ++c)
                gload16(Ab + (size_t)(bm * 128 + srow[c]) * alda + soff[c], Adst + c * 512);
            if (wid < 4) {
#pragma unroll
                for (int c = 0; c < 4; ++c)
                    gload16(d.W + (size_t)(bn * 64 + srow[c]) * d.ldw + d.woff + k0 + soff[c], Bdst + c * 512);
            }
        }
        __syncthreads();   // vmcnt drain (loads landed in LDS) + barrier
#pragma unroll
        for (int kk = 0; kk < 4; ++kk) {
            int gran = kk * 4 + lk;                               // 0..15
            int off = (gran >> 3) * 64 + (((gran & 7) ^ sw) * 8);
            bs8 a0 = *(const bs8*)(Ash + (wr * 32 + la) * 128      + off);
            bs8 a1 = *(const bs8*)(Ash + (wr * 32 + 16 + la) * 128 + off);
            bs8 b0 = *(const bs8*)(Bsh + (wc * 32 + la) * 128      + off);
            bs8 b1 = *(const bs8*)(Bsh + (wc * 32 + 16 + la) * 128 + off);
            acc[0][0] = __builtin_amdgcn_mfma_f32_16x16x32_bf16(a0, b0, acc[0][0], 0, 0, 0);
            acc[0][1] = __builtin_amdgcn_mfma_f32_16x16x32_bf16(a0, b1, acc[0][1], 0, 0, 0);
            acc[1][0] = __builtin_amdgcn_mfma_f32_16x16x32_bf16(a1, b0, acc[1][0], 0, 0, 0);
            acc[1][1] = __builtin_amdgcn_mfma_f32_16x16x32_bf16(a1, b1, acc[1][1], 0, 0, 0);
            if (split) {
                bs8 xl0 = *(const bs8*)(Asl + (wr * 32 + la) * 128      + off);
                bs8 xl1 = *(const bs8*)(Asl + (wr * 32 + 16 + la) * 128 + off);
                bs8 yl0 = *(const bs8*)(Bsl + (wc * 32 + la) * 128      + off);
                bs8 yl1 = *(const bs8*)(Bsl + (wc * 32 + 16 + la) * 128 + off);
                acc[0][0] = __builtin_amdgcn_mfma_f32_16x16x32_bf16(a0, yl0, acc[0][0], 0, 0, 0);
                acc[0][0] = __builtin_amdgcn_mfma_f32_16x16x32_bf16(xl0, b0, acc[0][0], 0, 0, 0);
                acc[0][1] = __builtin_amdgcn_mfma_f32_16x16x32_bf16(a0, yl1, acc[0][1], 0, 0, 0);
                acc[0][1] = __builtin_amdgcn_mfma_f32_16x16x32_bf16(xl0, b1, acc[0][1], 0, 0, 0);
                acc[1][0] = __builtin_amdgcn_mfma_f32_16x16x32_bf16(a1, yl0, acc[1][0], 0, 0, 0);
                acc[1][0] = __builtin_amdgcn_mfma_f32_16x16x32_bf16(xl1, b0, acc[1][0], 0, 0, 0);
                acc[1][1] = __builtin_amdgcn_mfma_f32_16x16x32_bf16(a1, yl1, acc[1][1], 0, 0, 0);
                acc[1][1] = __builtin_amdgcn_mfma_f32_16x16x32_bf16(xl1, b1, acc[1][1], 0, 0, 0);
            }
        }
    }

    const int rowb = (lane >> 4) * 4, coln = lane & 15;
    const bool accum = (d.flags & 2) != 0;
#pragma unroll
    for (int i = 0; i < 2; ++i)
#pragma unroll
    for (int j = 0; j < 2; ++j)
#pragma unroll
    for (int r = 0; r < 4; ++r) {
        int row = bm * 128 + wr * 32 + i * 16 + rowb + r;
        int col = bn * 64 + wc * 32 + j * 16 + coln;
        size_t idx = (size_t)row * d.ldc + col;
        if (accum) d.C[idx] += acc[i][j][r];
        else       d.C[idx]  = acc[i][j][r];
    }
}

// ---------------------------------------------------------------------------
// Split-T flash attention (unchanged).
// ---------------------------------------------------------------------------
__global__ __launch_bounds__(256) void k_attnp(const float* __restrict__ x_,
                                               const float* __restrict__ gh,
                                               float* __restrict__ ctxp,
                                               float2* __restrict__ msb) {
    int blk = blockIdx.x;
    int b = blk & (BB - 1), ch = blk >> 8;
    int tid = threadIdx.x, w = tid >> 6, lane = tid & 63;
    __shared__ float wm[4], ws[4];
    __shared__ float part[4][GG];

    const float* xb = x_ + (size_t)b * GG + lane * 8;
    float4 xa = *(const float4*)xb;
    float4 xc = *(const float4*)(xb + 4);

    float m = -INFINITY, s = 0.f;
    float acc[8] = {};
    int t0 = ch * 32 + w * 8;
#pragma unroll
    for (int it = 0; it < 8; ++it) {
        int t = t0 + it;
        const float* row = gh + ((size_t)t * BB + b) * GG + lane * 8;
        float4 v1 = *(const float4*)row;
        float4 v2 = *(const float4*)(row + 4);
        float p = v1.x*xa.x + v1.y*xa.y + v1.z*xa.z + v1.w*xa.w
                + v2.x*xc.x + v2.y*xc.y + v2.z*xc.z + v2.w*xc.w;
#pragma unroll
        for (int off = 32; off; off >>= 1) p += __shfl_xor(p, off);
        float nm = fmaxf(m, p);
        float scale = expf(m - nm);
        float e = expf(p - nm);
        s = s * scale + e;
        acc[0] = acc[0]*scale + e*v1.x; acc[1] = acc[1]*scale + e*v1.y;
        acc[2] = acc[2]*scale + e*v1.z; acc[3] = acc[3]*scale + e*v1.w;
        acc[4] = acc[4]*scale + e*v2.x; acc[5] = acc[5]*scale + e*v2.y;
        acc[6] = acc[6]*scale + e*v2.z; acc[7] = acc[7]*scale + e*v2.w;
        m = nm;
    }
    if (lane == 0) { wm[w] = m; ws[w] = s; }
    *(float4*)&part[w][lane * 8]     = make_float4(acc[0], acc[1], acc[2], acc[3]);
    *(float4*)&part[w][lane * 8 + 4] = make_float4(acc[4], acc[5], acc[6], acc[7]);
    __syncthreads();

    float M = fmaxf(fmaxf(wm[0], wm[1]), fmaxf(wm[2], wm[3]));
    float f0 = expf(wm[0] - M), f1 = expf(wm[1] - M);
    float f2 = expf(wm[2] - M), f3 = expf(wm[3] - M);
    if (tid == 0) {
        float S = ws[0]*f0 + ws[1]*f1 + ws[2]*f2 + ws[3]*f3;
        msb[blk] = make_float2(M, S);
    }
    for (int j = tid; j < GG; j += 256) {
        float r = part[0][j]*f0 + part[1][j]*f1 + part[2][j]*f2 + part[3][j]*f3;
        ctxp[(size_t)blk * GG + j] = r;
    }
}

// merge 8 chunk-partials per b -> ctx_bf
__global__ __launch_bounds__(256) void k_attnm(const float* __restrict__ ctxp,
                                               const float2* __restrict__ msb,
                                               short* __restrict__ ctx_bf) {
    int b = blockIdx.x, tid = threadIdx.x;
    float mv[8], sv[8];
    float M = -INFINITY;
#pragma unroll
    for (int c = 0; c < 8; ++c) {
        float2 t = msb[c * BB + b];
        mv[c] = t.x; sv[c] = t.y;
        M = fmaxf(M, t.x);
    }
    float S = 0.f;
    float f[8];
#pragma unroll
    for (int c = 0; c < 8; ++c) { f[c] = expf(mv[c] - M); S += sv[c] * f[c]; }
    float inv = 1.0f / S;
#pragma unroll
    for (int c = 0; c < 8; ++c) f[c] *= inv;
    for (int j = tid; j < GG; j += 256) {
        float r = 0.f;
#pragma unroll
        for (int c = 0; c < 8; ++c) r += ctxp[(size_t)(c * BB + b) * GG + j] * f[c];
        ctx_bf[(size_t)b * GG + j] = f2bf(r);
    }
}

// ---------------------------------------------------------------------------
// Fused GRU pair: [0, B*G) -> global GRU; [B*G, B*G+B*S) -> parties GRU
// ---------------------------------------------------------------------------
__global__ __launch_bounds__(256) void k_gru2(
        const float* __restrict__ gi_g, const float* __restrict__ gh_g,
        const float* __restrict__ bg_ih, const float* __restrict__ bg_hh,
        const float* __restrict__ hg, float* __restrict__ global_out,
        const float* __restrict__ gi_p, const float* __restrict__ gh_p,
        const float* __restrict__ bp_ih, const float* __restrict__ bp_hh,
        const float* __restrict__ sel0, const int* __restrict__ spk,
        short* __restrict__ par_bf, float* __restrict__ speaker_out) {
    int idx = blockIdx.x * 256 + threadIdx.x;
    if (idx < BB * GG) {
        int b = idx / GG, j = idx - b * GG;
        const float* gib = gi_g + (size_t)b * 3 * GG;
        const float* ghb = gh_g + (size_t)b * 3 * GG;
        float r = sigmoidf_(gib[j] + bg_ih[j] + ghb[j] + bg_hh[j]);
        float z = sigmoidf_(gib[GG + j] + bg_ih[GG + j] + ghb[GG + j] + bg_hh[GG + j]);
        float n = tanhf(gib[2*GG + j] + bg_ih[2*GG + j] + r * (ghb[2*GG + j] + bg_hh[2*GG + j]));
        global_out[idx] = (1.0f - z) * n + z * hg[idx];
    } else {
        idx -= BB * GG;
        int b = idx / SS, j = idx - b * SS;
        const float* gib = gi_p + (size_t)b * 3 * SS;
        const float* ghb = gh_p + (size_t)b * 3 * SS;
        float r = sigmoidf_(gib[j] + bp_ih[j] + ghb[j] + bp_hh[j]);
        float z = sigmoidf_(gib[SS + j] + bp_ih[SS + j] + ghb[SS + j] + bp_hh[SS + j]);
        float n = tanhf(gib[2*SS + j] + bp_ih[2*SS + j] + r * (ghb[2*SS + j] + bp_hh[2*SS + j]));
        float o = (1.0f - z) * n + z * sel0[idx];
        par_bf[idx] = f2bf(o);
        speaker_out[((size_t)b * PP + spk[b]) * SS + j] = o;
    }
}

// emotion GRU
__global__ __launch_bounds__(256) void k_gru(const float* __restrict__ gi, const float* __restrict__ gh,
                                             const float* __restrict__ bih, const float* __restrict__ bhh,
                                             const float* __restrict__ h,
                                             float* __restrict__ out, int H) {
    int idx = blockIdx.x * 256 + threadIdx.x;
    int b = idx / H, j = idx - b * H;
    const float* gib = gi + (size_t)b * 3 * H;
    const float* ghb = gh + (size_t)b * 3 * H;
    float r = sigmoidf_(gib[j] + bih[j] + ghb[j] + bhh[j]);
    float z = sigmoidf_(gib[H + j] + bih[H + j] + ghb[H + j] + bhh[H + j]);
    float n = tanhf(gib[2 * H + j] + bih[2 * H + j] + r * (ghb[2 * H + j] + bhh[2 * H + j]));
    out[idx] = (1.0f - z) * n + z * h[idx];
}

// ---------------------------------------------------------------------------
extern "C" void kernel_launch(void* const* d_in, const int* in_sizes, int n_in,
                              void* d_out, int out_size, void* d_ws, size_t ws_size,
                              hipStream_t stream) {
    const float* feature_ = (const float*)d_in[0];
    const float* mask     = (const float*)d_in[1];
    const float* ghist    = (const float*)d_in[2];
    const float* speaker0 = (const float*)d_in[3];
    const float* emotion0 = (const float*)d_in[4];
    const float* Wg_ih    = (const float*)d_in[5];
    const float* Wg_hh    = (const float*)d_in[6];
    const float* bg_ih    = (const float*)d_in[7];
    const float* bg_hh    = (const float*)d_in[8];
    const float* Wp_ih    = (const float*)d_in[9];
    const float* Wp_hh    = (const float*)d_in[10];
    const float* bp_ih    = (const float*)d_in[11];
    const float* bp_hh    = (const float*)d_in[12];
    const float* We_ih    = (const float*)d_in[13];
    const float* We_hh    = (const float*)d_in[14];
    const float* be_ih    = (const float*)d_in[15];
    const float* be_hh    = (const float*)d_in[16];
    const float* attn_W   = (const float*)d_in[17];

    float* out = (float*)d_out;
    float* emotion_out = out;
    float* global_out  = out + (size_t)BB * EE;
    float* speaker_out = global_out + (size_t)BB * GG;

    char* cur = (char*)d_ws;
    short* Wbf     = (short*)cur; cur += (size_t)WTOT * 2;
    short* awhi    = (short*)cur; cur += (size_t)GG * FF * 2;
    short* awlo    = (short*)cur; cur += (size_t)GG * FF * 2;
    short* xg      = (short*)cur; cur += (size_t)BB * 1536 * 2;
    short* fhi     = (short*)cur; cur += (size_t)BB * FF * 2;
    short* flo     = (short*)cur; cur += (size_t)BB * FF * 2;
    short* hg_bf   = (short*)cur; cur += (size_t)BB * GG * 2;
    short* emo_bf  = (short*)cur; cur += (size_t)BB * EE * 2;
    short* sel0_bf = (short*)cur; cur += (size_t)BB * SS * 2;
    short* ctx_bf  = (short*)cur; cur += (size_t)BB * GG * 2;
    short* par_bf  = (short*)cur; cur += (size_t)BB * SS * 2;

    float* sel0    = (float*)cur; cur += (size_t)BB * SS * 4;
    float* x_      = (float*)cur; cur += (size_t)BB * GG * 4;
    float* ctxp    = (float*)cur; cur += (size_t)2048 * GG * 4;
    float2* msb    = (float2*)cur; cur += (size_t)2048 * 8;
    float* gi_g    = (float*)cur; cur += (size_t)BB * 3 * GG * 4;
    float* gh_g    = (float*)cur; cur += (size_t)BB * 3 * GG * 4;
    float* gi_p    = (float*)cur; cur += (size_t)BB * 3 * SS * 4;
    float* gh_p    = (float*)cur; cur += (size_t)BB * 3 * SS * 4;
    float* gi_e    = (float*)cur; cur += (size_t)BB * 3 * EE * 4;
    float* gh_e    = (float*)cur; cur += (size_t)BB * 3 * EE * 4;
    int*   spk     = (int*)cur;   cur += 256 * 4;

    const float* h_g = ghist + (size_t)(TT - 1) * BB * GG;

    short* Wg_ih_bf = Wbf + OWG_IH;
    short* Wg_hh_bf = Wbf + OWG_HH;
    short* Wp_ih_bf = Wbf + OWP_IH;
    short* Wp_hh_bf = Wbf + OWP_HH;
    short* We_ih_bf = Wbf + OWE_IH;
    short* We_hh_bf = Wbf + OWE_HH;

    // 1) conversions + gather + speaker copy
    k_mega<<<MBE, 256, 0, stream>>>(Wg_ih, Wg_hh, Wp_ih, Wp_hh, We_ih, We_hh,
                                    attn_W, feature_, h_g, emotion0, mask, speaker0,
                                    Wbf, awhi, awlo, xg, fhi, flo, hg_bf, emo_bf,
                                    sel0_bf, sel0, spk, speaker_out);

    // 2) batchA: x_(split) + all attention-independent GEMMs (BM=128 tiles)
    GBatch gbA;
    gbA.d[0] = { fhi, flo, awhi, awlo, x_, FF, FF, FF, FF, 0, GG, FF, 8, 1 };
    gbA.d[1] = { xg, xg, Wg_ih_bf, nullptr, gi_g, 1536, 1536, 1536, 1536, 0, 3*GG, 1536, 24, 0 };
    gbA.d[2] = { hg_bf, hg_bf, Wg_hh_bf, nullptr, gh_g, GG, GG, GG, GG, 0, 3*GG, GG, 24, 0 };
    gbA.d[3] = { sel0_bf, sel0_bf, Wp_hh_bf, nullptr, gh_p, SS, SS, SS, SS, 0, 3*SS, SS, 24, 0 };
    gbA.d[4] = { emo_bf, emo_bf, We_hh_bf, nullptr, gh_e, EE, EE, EE, EE, 0, 3*EE, EE, 12, 0 };
    gbA.d[5] = { xg, xg, Wp_ih_bf, nullptr, gi_p, 1536, 1536, 1536, 1536, 0, 3*SS, FF, 24, 0 };
    gbA.start[0] = 0;   gbA.start[1] = 16;  gbA.start[2] = 64;  gbA.start[3] = 112;
    gbA.start[4] = 160; gbA.start[5] = 184; gbA.start[6] = 232;
    gbA.ng = 6;
    k_bgemm<<<232, 512, 0, stream>>>(gbA);

    // 3) flash attention partials (single history read)
    k_attnp<<<2048, 256, 0, stream>>>(x_, ghist, ctxp, msb);

    // 4) merge partials -> ctx_bf
    k_attnm<<<BB, 256, 0, stream>>>(ctxp, msb, ctx_bf);

    // 5) gi_p += ctx @ Wp_ih[:, F:]^T (accumulate)
    GBatch gbB;
    gbB.d[0] = { ctx_bf, ctx_bf, Wp_ih_bf, nullptr, gi_p, GG, GG, GG, 1536, FF, 3*SS, GG, 24, 2 };
    gbB.start[0] = 0; gbB.start[1] = 48; gbB.ng = 1;
    k_bgemm<<<48, 512, 0, stream>>>(gbB);

    // 6) global GRU + parties GRU (+ scatter)
    k_gru2<<<(BB * GG + BB * SS) / 256, 256, 0, stream>>>(
        gi_g, gh_g, bg_ih, bg_hh, h_g, global_out,
        gi_p, gh_p, bp_ih, bp_hh, sel0, spk, par_bf, speaker_out);

    // 7) gi_e = parties @ We_ih^T
    GBatch gbC;
    gbC.d[0] = { par_bf, par_bf, We_ih_bf, nullptr, gi_e, SS, SS, SS, SS, 0, 3*EE, SS, 12, 0 };
    gbC.start[0] = 0; gbC.start[1] = 24; gbC.ng = 1;
    k_bgemm<<<24, 512, 0, stream>>>(gbC);

    // 8) emotion GRU
    k_gru<<<(BB * EE) / 256, 256, 0, stream>>>(gi_e, gh_e, be_ih, be_hh, emotion0, emotion_out, EE);
}

// Round 16
// 89.915 us; speedup vs baseline: 1.0618x; 1.0618x over previous
//
#include <hip/hip_runtime.h>
#include <hip/hip_bf16.h>
#include <math.h>

#define BB 256
#define FF 1024
#define GG 512
#define SS 512
#define EE 256
#define PP 8
#define TT 256

typedef __attribute__((ext_vector_type(8))) short bs8;     // 8 bf16
typedef __attribute__((ext_vector_type(4))) float f32x4;

__device__ __forceinline__ float sigmoidf_(float x) { return 1.0f / (1.0f + expf(-x)); }

__device__ __forceinline__ short f2bf(float f) {
    union { float f; unsigned u; } v; v.f = f;
    unsigned r = v.u + 0x7FFFu + ((v.u >> 16) & 1u);   // RNE
    return (short)(r >> 16);
}

union BPack { bs8 s; __hip_bfloat162 h[4]; };

__device__ __forceinline__ bs8 ld8cvt(const float* p) {
    float4 a = *(const float4*)p, b = *(const float4*)(p + 4);
    BPack u;
    u.h[0] = __float22bfloat162_rn({a.x, a.y});
    u.h[1] = __float22bfloat162_rn({a.z, a.w});
    u.h[2] = __float22bfloat162_rn({b.x, b.y});
    u.h[3] = __float22bfloat162_rn({b.z, b.w});
    return u.s;
}
__device__ __forceinline__ void ld8split(const float* p, bs8& ho, bs8& lo) {
    float4 a = *(const float4*)p, b = *(const float4*)(p + 4);
    float v[8] = {a.x, a.y, a.z, a.w, b.x, b.y, b.z, b.w};
    BPack uh, ul;
#pragma unroll
    for (int j = 0; j < 4; ++j) {
        __hip_bfloat162 h2 = __float22bfloat162_rn({v[2*j], v[2*j+1]});
        uh.h[j] = h2;
        float r0 = v[2*j]   - __low2float(h2);
        float r1 = v[2*j+1] - __high2float(h2);
        ul.h[j] = __float22bfloat162_rn({r0, r1});
    }
    ho = uh.s; lo = ul.s;
}

// async global->LDS, 16B per lane, linear LDS dest (wave-uniform base + lane*16)
__device__ __forceinline__ void gload16(const short* g, short* l) {
    __builtin_amdgcn_global_load_lds(
        (const __attribute__((address_space(1))) void*)g,
        (__attribute__((address_space(3))) void*)l,
        16, 0, 0);
}

// ---------------------------------------------------------------------------
// W slab layout (elements)
// ---------------------------------------------------------------------------
#define OWG_IH 0L
#define OWG_HH 2359296L
#define OWP_IH 3145728L
#define OWP_HH 5505024L
#define OWE_IH 6291456L
#define OWE_HH 6684672L
#define WTOT   6881280L

// block-range boundaries for k_mega
#define MB1 3360     // W slab conv          (3360 blocks)
#define MB2 3616     // attn_W hi/lo split   (256)
#define MB3 3744     // feature -> xg/fhi/flo(128)
#define MB4 3808     // h_g -> hg_bf         (64)
#define MB5 3840     // emotion0 -> emo_bf   (32)
#define MB6 4096     // gather               (256)
#define MBE 5120     // speaker copy         (1024)

__global__ __launch_bounds__(256) void k_mega(
        const float* __restrict__ Wg_ih, const float* __restrict__ Wg_hh,
        const float* __restrict__ Wp_ih, const float* __restrict__ Wp_hh,
        const float* __restrict__ We_ih, const float* __restrict__ We_hh,
        const float* __restrict__ attn_W, const float* __restrict__ feature_,
        const float* __restrict__ h_g, const float* __restrict__ emotion0,
        const float* __restrict__ mask, const float* __restrict__ sp0,
        short* __restrict__ Wbf, short* __restrict__ awhi, short* __restrict__ awlo,
        short* __restrict__ xg, short* __restrict__ fhi, short* __restrict__ flo,
        short* __restrict__ hg_bf, short* __restrict__ emo_bf, short* __restrict__ sel0_bf,
        float* __restrict__ sel0, int* __restrict__ spk, float* __restrict__ speaker_out) {
    int blk = blockIdx.x, tid = threadIdx.x;
    if (blk < MB1) {
        long i = (long)blk * 2048 + tid * 8;
        const float* src; long base;
        if      (i < OWG_HH) { src = Wg_ih; base = OWG_IH; }
        else if (i < OWP_IH) { src = Wg_hh; base = OWG_HH; }
        else if (i < OWP_HH) { src = Wp_ih; base = OWP_IH; }
        else if (i < OWE_IH) { src = Wp_hh; base = OWP_HH; }
        else if (i < OWE_HH) { src = We_ih; base = OWE_IH; }
        else                 { src = We_hh; base = OWE_HH; }
        *(bs8*)(Wbf + i) = ld8cvt(src + (i - base));
    } else if (blk < MB2) {
        long i = (long)(blk - MB1) * 2048 + tid * 8;
        bs8 h, l;
        ld8split(attn_W + i, h, l);
        *(bs8*)(awhi + i) = h;
        *(bs8*)(awlo + i) = l;
    } else if (blk < MB3) {
        long i = (long)(blk - MB2) * 2048 + tid * 8;
        bs8 h, l;
        ld8split(feature_ + i, h, l);
        *(bs8*)(fhi + i) = h;
        *(bs8*)(flo + i) = l;
        long b = i >> 10, c = i & 1023;
        *(bs8*)(xg + b * 1536 + c) = h;
    } else if (blk < MB4) {
        long i = (long)(blk - MB3) * 2048 + tid * 8;
        *(bs8*)(hg_bf + i) = ld8cvt(h_g + i);
    } else if (blk < MB5) {
        long i = (long)(blk - MB4) * 2048 + tid * 8;
        *(bs8*)(emo_bf + i) = ld8cvt(emotion0 + i);
    } else if (blk < MB6) {
        int b = blk - MB5;
        __shared__ int sid;
        if (tid == 0) {
            int best = 0; float bv = mask[b * PP];
            for (int p = 1; p < PP; ++p) { float v = mask[b * PP + p]; if (v > bv) { bv = v; best = p; } }
            sid = best; spk[b] = best;
        }
        __syncthreads();
        const float* src = sp0 + ((size_t)b * PP + sid) * SS;
        for (int j = tid; j < SS; j += 256) {
            float v = src[j];
            sel0[(size_t)b * SS + j] = v;
            short h = f2bf(v);
            sel0_bf[(size_t)b * SS + j] = h;
            xg[(size_t)b * 1536 + FF + j] = h;
        }
    } else {
        size_t i = ((size_t)(blk - MB6) * 256 + tid) * 4;
        *(float4*)(speaker_out + i) = *(const float4*)(sp0 + i);
    }
}

// ---------------------------------------------------------------------------
// Batched bf16 MFMA GEMM. global_load_lds staging (width 16), pre-swizzled
// global source, BK=128 (two 64-col chunks per stage; one barrier pair per
// 128 cols). Bit-identical bytes/order vs the BK=64 version.
// flags: 1 = split (A2=A_lo, Wl=W_lo; 3-MFMA compensated), 2 = accumulate.
// ---------------------------------------------------------------------------
struct GDesc {
    const short *A, *A2, *W, *Wl;
    float* C;
    int lda, lda2, kb, ldw, woff, ldc, K, nbn, flags;
};
struct GBatch {
    GDesc d[6];
    int start[7];
    int ng;
};

__global__ __launch_bounds__(256) void k_bgemm(GBatch gb) {
    __shared__ __align__(16) short Ash[8192], Bsh[8192];   // 64 x 128 each
    __shared__ __align__(16) short Asl[8192], Bsl[8192];

    int bid = blockIdx.x;
    int g = 0;
    while (g + 1 < gb.ng && bid >= gb.start[g + 1]) ++g;
    GDesc d = gb.d[g];
    int local = bid - gb.start[g];
    int bn = local % d.nbn, bm = local / d.nbn;
    const bool split = (d.flags & 1) != 0;

    const int tid = threadIdx.x;
    const int lane = tid & 63, wid = tid >> 6;
    const int wr = wid >> 1, wc = wid & 1;
    const int la = lane & 15, lk = lane >> 4;
    const int sw = la & 7;

    // staging map: wave wid covers rows [wid*16, wid*16+16) of the 64x128
    // tile; instr c covers rows wid*16 + c*4 + lane/16, granule lane&15.
    int srow[4], soff[4];
#pragma unroll
    for (int c = 0; c < 4; ++c) {
        srow[c] = wid * 16 + c * 4 + (lane >> 4);
        int gq = lane & 15;
        soff[c] = (gq >> 3) * 64 + (((gq & 7) ^ (srow[c] & 7)) * 8);  // pre-swizzled
    }
    short* Adst  = Ash + wid * 2048;
    short* Bdst  = Bsh + wid * 2048;
    short* Aldst = Asl + wid * 2048;
    short* Bldst = Bsl + wid * 2048;

    f32x4 acc[2][2] = {};

    for (int k0 = 0; k0 < d.K; k0 += 128) {
        __syncthreads();   // previous iteration's LDS reads complete
        if (split) {
#pragma unroll
            for (int c = 0; c < 4; ++c) {
                size_t oa = (size_t)(bm * 64 + srow[c]) * d.lda + k0 + soff[c];
                size_t ow = (size_t)(bn * 64 + srow[c]) * d.ldw + d.woff + k0 + soff[c];
                gload16(d.A  + oa, Adst  + c * 512);
                gload16(d.A2 + oa, Aldst + c * 512);
                gload16(d.W  + ow, Bdst  + c * 512);
                gload16(d.Wl + ow, Bldst + c * 512);
            }
        } else {
            const short* Ab; int alda;
            if (k0 < d.kb) { Ab = d.A + k0; alda = d.lda; }
            else           { Ab = d.A2 + (k0 - d.kb); alda = d.lda2; }
#pragma unroll
            for (int c = 0; c < 4; ++c) {
                gload16(Ab + (size_t)(bm * 64 + srow[c]) * alda + soff[c], Adst + c * 512);
                gload16(d.W + (size_t)(bn * 64 + srow[c]) * d.ldw + d.woff + k0 + soff[c], Bdst + c * 512);
            }
        }
        __syncthreads();   // vmcnt drain (loads landed in LDS) + barrier
#pragma unroll
        for (int kk = 0; kk < 4; ++kk) {
            int gran = kk * 4 + lk;                               // 0..15
            int off = (gran >> 3) * 64 + (((gran & 7) ^ sw) * 8);
            bs8 a0 = *(const bs8*)(Ash + (wr * 32 + la) * 128      + off);
            bs8 a1 = *(const bs8*)(Ash + (wr * 32 + 16 + la) * 128 + off);
            bs8 b0 = *(const bs8*)(Bsh + (wc * 32 + la) * 128      + off);
            bs8 b1 = *(const bs8*)(Bsh + (wc * 32 + 16 + la) * 128 + off);
            acc[0][0] = __builtin_amdgcn_mfma_f32_16x16x32_bf16(a0, b0, acc[0][0], 0, 0, 0);
            acc[0][1] = __builtin_amdgcn_mfma_f32_16x16x32_bf16(a0, b1, acc[0][1], 0, 0, 0);
            acc[1][0] = __builtin_amdgcn_mfma_f32_16x16x32_bf16(a1, b0, acc[1][0], 0, 0, 0);
            acc[1][1] = __builtin_amdgcn_mfma_f32_16x16x32_bf16(a1, b1, acc[1][1], 0, 0, 0);
            if (split) {
                bs8 xl0 = *(const bs8*)(Asl + (wr * 32 + la) * 128      + off);
                bs8 xl1 = *(const bs8*)(Asl + (wr * 32 + 16 + la) * 128 + off);
                bs8 yl0 = *(const bs8*)(Bsl + (wc * 32 + la) * 128      + off);
                bs8 yl1 = *(const bs8*)(Bsl + (wc * 32 + 16 + la) * 128 + off);
                acc[0][0] = __builtin_amdgcn_mfma_f32_16x16x32_bf16(a0, yl0, acc[0][0], 0, 0, 0);
                acc[0][0] = __builtin_amdgcn_mfma_f32_16x16x32_bf16(xl0, b0, acc[0][0], 0, 0, 0);
                acc[0][1] = __builtin_amdgcn_mfma_f32_16x16x32_bf16(a0, yl1, acc[0][1], 0, 0, 0);
                acc[0][1] = __builtin_amdgcn_mfma_f32_16x16x32_bf16(xl0, b1, acc[0][1], 0, 0, 0);
                acc[1][0] = __builtin_amdgcn_mfma_f32_16x16x32_bf16(a1, yl0, acc[1][0], 0, 0, 0);
                acc[1][0] = __builtin_amdgcn_mfma_f32_16x16x32_bf16(xl1, b0, acc[1][0], 0, 0, 0);
                acc[1][1] = __builtin_amdgcn_mfma_f32_16x16x32_bf16(a1, yl1, acc[1][1], 0, 0, 0);
                acc[1][1] = __builtin_amdgcn_mfma_f32_16x16x32_bf16(xl1, b1, acc[1][1], 0, 0, 0);
            }
        }
    }

    const int rowb = (lane >> 4) * 4, coln = lane & 15;
    const bool accum = (d.flags & 2) != 0;
#pragma unroll
    for (int i = 0; i < 2; ++i)
#pragma unroll
    for (int j = 0; j < 2; ++j)
#pragma unroll
    for (int r = 0; r < 4; ++r) {
        int row = bm * 64 + wr * 32 + i * 16 + rowb + r;
        int col = bn * 64 + wc * 32 + j * 16 + coln;
        size_t idx = (size_t)row * d.ldc + col;
        if (accum) d.C[idx] += acc[i][j][r];
        else       d.C[idx]  = acc[i][j][r];
    }
}

// ---------------------------------------------------------------------------
// Split-T flash attention (unchanged).
// ---------------------------------------------------------------------------
__global__ __launch_bounds__(256) void k_attnp(const float* __restrict__ x_,
                                               const float* __restrict__ gh,
                                               float* __restrict__ ctxp,
                                               float2* __restrict__ msb) {
    int blk = blockIdx.x;
    int b = blk & (BB - 1), ch = blk >> 8;
    int tid = threadIdx.x, w = tid >> 6, lane = tid & 63;
    __shared__ float wm[4], ws[4];
    __shared__ float part[4][GG];

    const float* xb = x_ + (size_t)b * GG + lane * 8;
    float4 xa = *(const float4*)xb;
    float4 xc = *(const float4*)(xb + 4);

    float m = -INFINITY, s = 0.f;
    float acc[8] = {};
    int t0 = ch * 32 + w * 8;
#pragma unroll
    for (int it = 0; it < 8; ++it) {
        int t = t0 + it;
        const float* row = gh + ((size_t)t * BB + b) * GG + lane * 8;
        float4 v1 = *(const float4*)row;
        float4 v2 = *(const float4*)(row + 4);
        float p = v1.x*xa.x + v1.y*xa.y + v1.z*xa.z + v1.w*xa.w
                + v2.x*xc.x + v2.y*xc.y + v2.z*xc.z + v2.w*xc.w;
#pragma unroll
        for (int off = 32; off; off >>= 1) p += __shfl_xor(p, off);
        float nm = fmaxf(m, p);
        float scale = expf(m - nm);
        float e = expf(p - nm);
        s = s * scale + e;
        acc[0] = acc[0]*scale + e*v1.x; acc[1] = acc[1]*scale + e*v1.y;
        acc[2] = acc[2]*scale + e*v1.z; acc[3] = acc[3]*scale + e*v1.w;
        acc[4] = acc[4]*scale + e*v2.x; acc[5] = acc[5]*scale + e*v2.y;
        acc[6] = acc[6]*scale + e*v2.z; acc[7] = acc[7]*scale + e*v2.w;
        m = nm;
    }
    if (lane == 0) { wm[w] = m; ws[w] = s; }
    *(float4*)&part[w][lane * 8]     = make_float4(acc[0], acc[1], acc[2], acc[3]);
    *(float4*)&part[w][lane * 8 + 4] = make_float4(acc[4], acc[5], acc[6], acc[7]);
    __syncthreads();

    float M = fmaxf(fmaxf(wm[0], wm[1]), fmaxf(wm[2], wm[3]));
    float f0 = expf(wm[0] - M), f1 = expf(wm[1] - M);
    float f2 = expf(wm[2] - M), f3 = expf(wm[3] - M);
    if (tid == 0) {
        float S = ws[0]*f0 + ws[1]*f1 + ws[2]*f2 + ws[3]*f3;
        msb[blk] = make_float2(M, S);
    }
    for (int j = tid; j < GG; j += 256) {
        float r = part[0][j]*f0 + part[1][j]*f1 + part[2][j]*f2 + part[3][j]*f3;
        ctxp[(size_t)blk * GG + j] = r;
    }
}

// merge 8 chunk-partials per b -> ctx_bf
__global__ __launch_bounds__(256) void k_attnm(const float* __restrict__ ctxp,
                                               const float2* __restrict__ msb,
                                               short* __restrict__ ctx_bf) {
    int b = blockIdx.x, tid = threadIdx.x;
    float mv[8], sv[8];
    float M = -INFINITY;
#pragma unroll
    for (int c = 0; c < 8; ++c) {
        float2 t = msb[c * BB + b];
        mv[c] = t.x; sv[c] = t.y;
        M = fmaxf(M, t.x);
    }
    float S = 0.f;
    float f[8];
#pragma unroll
    for (int c = 0; c < 8; ++c) { f[c] = expf(mv[c] - M); S += sv[c] * f[c]; }
    float inv = 1.0f / S;
#pragma unroll
    for (int c = 0; c < 8; ++c) f[c] *= inv;
    for (int j = tid; j < GG; j += 256) {
        float r = 0.f;
#pragma unroll
        for (int c = 0; c < 8; ++c) r += ctxp[(size_t)(c * BB + b) * GG + j] * f[c];
        ctx_bf[(size_t)b * GG + j] = f2bf(r);
    }
}

// ---------------------------------------------------------------------------
// Fused GRU pair: [0, B*G) -> global GRU; [B*G, B*G+B*S) -> parties GRU
// ---------------------------------------------------------------------------
__global__ __launch_bounds__(256) void k_gru2(
        const float* __restrict__ gi_g, const float* __restrict__ gh_g,
        const float* __restrict__ bg_ih, const float* __restrict__ bg_hh,
        const float* __restrict__ hg, float* __restrict__ global_out,
        const float* __restrict__ gi_p, const float* __restrict__ gh_p,
        const float* __restrict__ bp_ih, const float* __restrict__ bp_hh,
        const float* __restrict__ sel0, const int* __restrict__ spk,
        short* __restrict__ par_bf, float* __restrict__ speaker_out) {
    int idx = blockIdx.x * 256 + threadIdx.x;
    if (idx < BB * GG) {
        int b = idx / GG, j = idx - b * GG;
        const float* gib = gi_g + (size_t)b * 3 * GG;
        const float* ghb = gh_g + (size_t)b * 3 * GG;
        float r = sigmoidf_(gib[j] + bg_ih[j] + ghb[j] + bg_hh[j]);
        float z = sigmoidf_(gib[GG + j] + bg_ih[GG + j] + ghb[GG + j] + bg_hh[GG + j]);
        float n = tanhf(gib[2*GG + j] + bg_ih[2*GG + j] + r * (ghb[2*GG + j] + bg_hh[2*GG + j]));
        global_out[idx] = (1.0f - z) * n + z * hg[idx];
    } else {
        idx -= BB * GG;
        int b = idx / SS, j = idx - b * SS;
        const float* gib = gi_p + (size_t)b * 3 * SS;
        const float* ghb = gh_p + (size_t)b * 3 * SS;
        float r = sigmoidf_(gib[j] + bp_ih[j] + ghb[j] + bp_hh[j]);
        float z = sigmoidf_(gib[SS + j] + bp_ih[SS + j] + ghb[SS + j] + bp_hh[SS + j]);
        float n = tanhf(gib[2*SS + j] + bp_ih[2*SS + j] + r * (ghb[2*SS + j] + bp_hh[2*SS + j]));
        float o = (1.0f - z) * n + z * sel0[idx];
        par_bf[idx] = f2bf(o);
        speaker_out[((size_t)b * PP + spk[b]) * SS + j] = o;
    }
}

// emotion GRU
__global__ __launch_bounds__(256) void k_gru(const float* __restrict__ gi, const float* __restrict__ gh,
                                             const float* __restrict__ bih, const float* __restrict__ bhh,
                                             const float* __restrict__ h,
                                             float* __restrict__ out, int H) {
    int idx = blockIdx.x * 256 + threadIdx.x;
    int b = idx / H, j = idx - b * H;
    const float* gib = gi + (size_t)b * 3 * H;
    const float* ghb = gh + (size_t)b * 3 * H;
    float r = sigmoidf_(gib[j] + bih[j] + ghb[j] + bhh[j]);
    float z = sigmoidf_(gib[H + j] + bih[H + j] + ghb[H + j] + bhh[H + j]);
    float n = tanhf(gib[2 * H + j] + bih[2 * H + j] + r * (ghb[2 * H + j] + bhh[2 * H + j]));
    out[idx] = (1.0f - z) * n + z * h[idx];
}

// ---------------------------------------------------------------------------
extern "C" void kernel_launch(void* const* d_in, const int* in_sizes, int n_in,
                              void* d_out, int out_size, void* d_ws, size_t ws_size,
                              hipStream_t stream) {
    const float* feature_ = (const float*)d_in[0];
    const float* mask     = (const float*)d_in[1];
    const float* ghist    = (const float*)d_in[2];
    const float* speaker0 = (const float*)d_in[3];
    const float* emotion0 = (const float*)d_in[4];
    const float* Wg_ih    = (const float*)d_in[5];
    const float* Wg_hh    = (const float*)d_in[6];
    const float* bg_ih    = (const float*)d_in[7];
    const float* bg_hh    = (const float*)d_in[8];
    const float* Wp_ih    = (const float*)d_in[9];
    const float* Wp_hh    = (const float*)d_in[10];
    const float* bp_ih    = (const float*)d_in[11];
    const float* bp_hh    = (const float*)d_in[12];
    const float* We_ih    = (const float*)d_in[13];
    const float* We_hh    = (const float*)d_in[14];
    const float* be_ih    = (const float*)d_in[15];
    const float* be_hh    = (const float*)d_in[16];
    const float* attn_W   = (const float*)d_in[17];

    float* out = (float*)d_out;
    float* emotion_out = out;
    float* global_out  = out + (size_t)BB * EE;
    float* speaker_out = global_out + (size_t)BB * GG;

    char* cur = (char*)d_ws;
    short* Wbf     = (short*)cur; cur += (size_t)WTOT * 2;
    short* awhi    = (short*)cur; cur += (size_t)GG * FF * 2;
    short* awlo    = (short*)cur; cur += (size_t)GG * FF * 2;
    short* xg      = (short*)cur; cur += (size_t)BB * 1536 * 2;
    short* fhi     = (short*)cur; cur += (size_t)BB * FF * 2;
    short* flo     = (short*)cur; cur += (size_t)BB * FF * 2;
    short* hg_bf   = (short*)cur; cur += (size_t)BB * GG * 2;
    short* emo_bf  = (short*)cur; cur += (size_t)BB * EE * 2;
    short* sel0_bf = (short*)cur; cur += (size_t)BB * SS * 2;
    short* ctx_bf  = (short*)cur; cur += (size_t)BB * GG * 2;
    short* par_bf  = (short*)cur; cur += (size_t)BB * SS * 2;

    float* sel0    = (float*)cur; cur += (size_t)BB * SS * 4;
    float* x_      = (float*)cur; cur += (size_t)BB * GG * 4;
    float* ctxp    = (float*)cur; cur += (size_t)2048 * GG * 4;
    float2* msb    = (float2*)cur; cur += (size_t)2048 * 8;
    float* gi_g    = (float*)cur; cur += (size_t)BB * 3 * GG * 4;
    float* gh_g    = (float*)cur; cur += (size_t)BB * 3 * GG * 4;
    float* gi_p    = (float*)cur; cur += (size_t)BB * 3 * SS * 4;
    float* gh_p    = (float*)cur; cur += (size_t)BB * 3 * SS * 4;
    float* gi_e    = (float*)cur; cur += (size_t)BB * 3 * EE * 4;
    float* gh_e    = (float*)cur; cur += (size_t)BB * 3 * EE * 4;
    int*   spk     = (int*)cur;   cur += 256 * 4;

    const float* h_g = ghist + (size_t)(TT - 1) * BB * GG;

    short* Wg_ih_bf = Wbf + OWG_IH;
    short* Wg_hh_bf = Wbf + OWG_HH;
    short* Wp_ih_bf = Wbf + OWP_IH;
    short* Wp_hh_bf = Wbf + OWP_HH;
    short* We_ih_bf = Wbf + OWE_IH;
    short* We_hh_bf = Wbf + OWE_HH;

    // 1) conversions + gather + speaker copy
    k_mega<<<MBE, 256, 0, stream>>>(Wg_ih, Wg_hh, Wp_ih, Wp_hh, We_ih, We_hh,
                                    attn_W, feature_, h_g, emotion0, mask, speaker0,
                                    Wbf, awhi, awlo, xg, fhi, flo, hg_bf, emo_bf,
                                    sel0_bf, sel0, spk, speaker_out);

    // 2) batchA: x_(split) + all attention-independent GEMMs
    GBatch gbA;
    gbA.d[0] = { fhi, flo, awhi, awlo, x_, FF, FF, FF, FF, 0, GG, FF, 8, 1 };
    gbA.d[1] = { xg, xg, Wg_ih_bf, nullptr, gi_g, 1536, 1536, 1536, 1536, 0, 3*GG, 1536, 24, 0 };
    gbA.d[2] = { hg_bf, hg_bf, Wg_hh_bf, nullptr, gh_g, GG, GG, GG, GG, 0, 3*GG, GG, 24, 0 };
    gbA.d[3] = { sel0_bf, sel0_bf, Wp_hh_bf, nullptr, gh_p, SS, SS, SS, SS, 0, 3*SS, SS, 24, 0 };
    gbA.d[4] = { emo_bf, emo_bf, We_hh_bf, nullptr, gh_e, EE, EE, EE, EE, 0, 3*EE, EE, 12, 0 };
    gbA.d[5] = { xg, xg, Wp_ih_bf, nullptr, gi_p, 1536, 1536, 1536, 1536, 0, 3*SS, FF, 24, 0 };
    gbA.start[0] = 0;   gbA.start[1] = 32;  gbA.start[2] = 128; gbA.start[3] = 224;
    gbA.start[4] = 320; gbA.start[5] = 368; gbA.start[6] = 464;
    gbA.ng = 6;
    k_bgemm<<<464, 256, 0, stream>>>(gbA);

    // 3) flash attention partials (single history read)
    k_attnp<<<2048, 256, 0, stream>>>(x_, ghist, ctxp, msb);

    // 4) merge partials -> ctx_bf
    k_attnm<<<BB, 256, 0, stream>>>(ctxp, msb, ctx_bf);

    // 5) gi_p += ctx @ Wp_ih[:, F:]^T (accumulate)
    GBatch gbB;
    gbB.d[0] = { ctx_bf, ctx_bf, Wp_ih_bf, nullptr, gi_p, GG, GG, GG, 1536, FF, 3*SS, GG, 24, 2 };
    gbB.start[0] = 0; gbB.start[1] = 96; gbB.ng = 1;
    k_bgemm<<<96, 256, 0, stream>>>(gbB);

    // 6) global GRU + parties GRU (+ scatter)
    k_gru2<<<(BB * GG + BB * SS) / 256, 256, 0, stream>>>(
        gi_g, gh_g, bg_ih, bg_hh, h_g, global_out,
        gi_p, gh_p, bp_ih, bp_hh, sel0, spk, par_bf, speaker_out);

    // 7) gi_e = parties @ We_ih^T
    GBatch gbC;
    gbC.d[0] = { par_bf, par_bf, We_ih_bf, nullptr, gi_e, SS, SS, SS, SS, 0, 3*EE, SS, 12, 0 };
    gbC.start[0] = 0; gbC.start[1] = 48; gbC.ng = 1;
    k_bgemm<<<48, 256, 0, stream>>>(gbC);

    // 8) emotion GRU
    k_gru<<<(BB * EE) / 256, 256, 0, stream>>>(gi_e, gh_e, be_ih, be_hh, emotion0, emotion_out, EE);
}